// Round 1
// baseline (675.538 us; speedup 1.0000x reference)
//
#include <hip/hip_runtime.h>
#include <math.h>

#define B_SIZE 8192
#define NVERT 778
#define NJOINT 16
#define NJ2 21
#define NP 135
#define NQ 1008  // 21*16*3

// workspace offsets (in floats)
#define OFF_VSHAPED 0        // 2334
#define OFF_JK      2336     // 48
#define OFF_REL     2384     // 48
#define OFF_C1      2432     // 336
#define OFF_C0      2768     // 1008
#define OFF_P       3776     // 135*1008 = 136080
#define OFF_S2      139856   // 336*778 = 261408
#define OFF_PF      401264   // 8192*135
#define OFF_A       1507184  // 8192*192
// total 3080048 floats = 12.32 MB

__device__ inline void quat2mat_dev(float qw, float qx, float qy, float qz, float* R) {
  float n = sqrtf(qw*qw + qx*qx + qy*qy + qz*qz);
  float w = qw/n, x = qx/n, y = qy/n, z = qz/n;
  float w2=w*w, x2=x*x, y2=y*y, z2=z*z;
  float wx=w*x, wy=w*y, wz=w*z, xy=x*y, xz=x*z, yz=y*z;
  R[0]=w2+x2-y2-z2; R[1]=2.f*xy-2.f*wz; R[2]=2.f*wy+2.f*xz;
  R[3]=2.f*wz+2.f*xy; R[4]=w2-x2+y2-z2; R[5]=2.f*yz-2.f*wx;
  R[6]=2.f*xz-2.f*wy; R[7]=2.f*wx+2.f*yz; R[8]=w2-x2-y2+z2;
}

__device__ inline void rodrigues_dev(float tx, float ty, float tz, float* R) {
  float ax = tx + 1e-8f, ay = ty + 1e-8f, az = tz + 1e-8f;
  float angle = sqrtf(ax*ax + ay*ay + az*az);
  float nx = tx/angle, ny = ty/angle, nz = tz/angle;
  float half = 0.5f*angle;
  float cw = cosf(half), sw = sinf(half);
  quat2mat_dev(cw, sw*nx, sw*ny, sw*nz, R);
}

// A[j] (3x4, rows) from G (r[9], t[3]) and Jk_j
__device__ inline void write_A(float* A, const float* G, const float* jk) {
  #pragma unroll
  for (int c = 0; c < 3; ++c) {
    float g0 = G[c*3+0], g1 = G[c*3+1], g2 = G[c*3+2];
    A[c*4+0] = g0; A[c*4+1] = g1; A[c*4+2] = g2;
    A[c*4+3] = G[9+c] - (g0*jk[0] + g1*jk[1] + g2*jk[2]);
  }
}

// K1: v_shaped, Jk (16 joints), rel  -- batch independent
__global__ void k1_shape(const float* __restrict__ user_shape,
                         const float* __restrict__ v_template,
                         const float* __restrict__ shapedirs,
                         const float* __restrict__ J_regressor,
                         float* __restrict__ ws) {
  __shared__ float sh[10];
  __shared__ float vs[NVERT*3];
  __shared__ float jk[48];
  int tid = threadIdx.x;
  if (tid < 10) sh[tid] = user_shape[tid];
  __syncthreads();
  for (int e = tid; e < NVERT*3; e += blockDim.x) {
    float acc = v_template[e];
    #pragma unroll
    for (int s = 0; s < 10; ++s) acc += sh[s]*shapedirs[s*2334 + e];
    vs[e] = acc;
    ws[OFF_VSHAPED + e] = acc;
  }
  __syncthreads();
  if (tid < 48) {
    int j = tid/3, c = tid - j*3;
    float acc = 0.f;
    for (int v = 0; v < NVERT; ++v) acc += vs[v*3+c]*J_regressor[v*21+j];
    jk[tid] = acc;
    ws[OFF_JK + tid] = acc;
  }
  __syncthreads();
  if (tid < 48) {
    int j = tid/3, c = tid - j*3;
    float r;
    if (j == 0) r = jk[c];
    else {
      int par = (((j-1) % 3) == 0) ? 0 : (j-1);
      r = jk[j*3+c] - jk[par*3+c];
    }
    ws[OFF_REL + tid] = r;
  }
}

// K2: S2[q2][v] = JR[v][j2]*W[v][j];  C1[q2], C0[q2*3+c]
__global__ void k2_s2(const float* __restrict__ J_regressor,
                      const float* __restrict__ weights,
                      float* __restrict__ ws) {
  int q2 = blockIdx.x;             // 0..335
  int j2 = q2 >> 4, j = q2 & 15;
  int tid = threadIdx.x;
  const float* vs = ws + OFF_VSHAPED;
  float* S2 = ws + OFF_S2;
  float c1 = 0.f, c0x = 0.f, c0y = 0.f, c0z = 0.f;
  for (int v = tid; v < NVERT; v += blockDim.x) {
    float s = J_regressor[v*21 + j2] * weights[v*16 + j];
    S2[q2*NVERT + v] = s;
    c1  += s;
    c0x += s*vs[v*3+0];
    c0y += s*vs[v*3+1];
    c0z += s*vs[v*3+2];
  }
  __shared__ float red[256][4];
  red[tid][0]=c1; red[tid][1]=c0x; red[tid][2]=c0y; red[tid][3]=c0z;
  __syncthreads();
  for (int s = 128; s > 0; s >>= 1) {
    if (tid < s) {
      red[tid][0]+=red[tid+s][0]; red[tid][1]+=red[tid+s][1];
      red[tid][2]+=red[tid+s][2]; red[tid][3]+=red[tid+s][3];
    }
    __syncthreads();
  }
  if (tid == 0) {
    ws[OFF_C1 + q2] = red[0][0];
    ws[OFF_C0 + q2*3+0] = red[0][1];
    ws[OFF_C0 + q2*3+1] = red[0][2];
    ws[OFF_C0 + q2*3+2] = red[0][3];
  }
}

// K3: P[p][q] = sum_v S2[q2][v]*posedirs[p][3v+c], q=q2*3+c. grid = 135*2
__global__ void k3_P(const float* __restrict__ posedirs, float* __restrict__ ws) {
  int p = blockIdx.x >> 1;
  int half = blockIdx.x & 1;
  int tid = threadIdx.x;
  __shared__ float row[2334];
  for (int i = tid; i < 2334; i += 256) row[i] = posedirs[p*2334 + i];
  __syncthreads();
  const float* S2 = ws + OFF_S2;
  float* P = ws + OFF_P;
  int o_end = half*504 + 504;
  for (int o = half*504 + tid; o < o_end; o += 256) {
    int q2 = o/3, c = o - q2*3;
    const float* s2r = S2 + q2*NVERT;
    float acc = 0.f;
    #pragma unroll 2
    for (int v = 0; v < NVERT; ++v) acc += s2r[v]*row[3*v + c];
    P[p*NQ + o] = acc;
  }
}

// K4: per (b, unit): unit 0..4 = kinematic chain of 3 joints (+pf rows), unit 5 = joint 0.
__global__ void k4_pose(const float* __restrict__ theta,
                        const float* __restrict__ delta_quat,
                        const float* __restrict__ init_quat,
                        float* __restrict__ ws) {
  int gid = blockIdx.x*blockDim.x + threadIdx.x;
  int b = gid/6, u = gid - b*6;
  if (b >= B_SIZE) return;
  const float* Jk  = ws + OFF_JK;
  const float* rel = ws + OFF_REL;
  float* pf   = ws + OFF_PF + (size_t)b*NP;
  float* Aout = ws + OFF_A  + (size_t)b*192;
  // root transform
  float w1=delta_quat[b*4+0], x1=delta_quat[b*4+1], y1=delta_quat[b*4+2], z1=delta_quat[b*4+3];
  float w2=init_quat[0], x2=init_quat[1], y2=init_quat[2], z2=init_quat[3];
  float qw = w1*w2 - x1*x2 - y1*y2 - z1*z2;
  float qx = w1*x2 + x1*w2 + y1*z2 - z1*y2;
  float qy = w1*y2 - x1*z2 + y1*w2 + z1*x2;
  float qz = w1*z2 + x1*y2 - y1*x2 + z1*w2;
  float G[12];
  quat2mat_dev(qw, qx, qy, qz, G);
  G[9]  = rel[0]; G[10] = rel[1]; G[11] = rel[2];
  if (u == 5) {
    write_A(Aout, G, Jk);   // joint 0
    return;
  }
  // chain u: joints 3u+1 .. 3u+3
  for (int mstep = 0; mstep < 3; ++mstep) {
    int j = 3*u + 1 + mstep;
    int i = j - 1;
    float tx = theta[b*45 + 3*i + 0];
    float ty = theta[b*45 + 3*i + 1];
    float tz = theta[b*45 + 3*i + 2];
    float R[9];
    rodrigues_dev(tx, ty, tz, R);
    pf[9*i+0] = R[0]-1.f; pf[9*i+1] = R[1];     pf[9*i+2] = R[2];
    pf[9*i+3] = R[3];     pf[9*i+4] = R[4]-1.f; pf[9*i+5] = R[5];
    pf[9*i+6] = R[6];     pf[9*i+7] = R[7];     pf[9*i+8] = R[8]-1.f;
    float nG[12];
    const float* rj = rel + j*3;
    #pragma unroll
    for (int r3 = 0; r3 < 3; ++r3) {
      float a0 = G[r3*3+0], a1 = G[r3*3+1], a2 = G[r3*3+2];
      nG[r3*3+0] = a0*R[0] + a1*R[3] + a2*R[6];
      nG[r3*3+1] = a0*R[1] + a1*R[4] + a2*R[7];
      nG[r3*3+2] = a0*R[2] + a1*R[5] + a2*R[8];
      nG[9+r3]   = G[9+r3] + a0*rj[0] + a1*rj[1] + a2*rj[2];
    }
    #pragma unroll
    for (int k = 0; k < 12; ++k) G[k] = nG[k];
    write_A(Aout + j*12, G, Jk + j*3);
  }
}

// K5: main fused kernel. Block = 12 batch x 21 out-joints.
__global__ __launch_bounds__(256) void k5_main(const float* __restrict__ init_trans,
                                               const float* __restrict__ ws,
                                               float* __restrict__ out) {
  const int NB = 12;
  int b0 = blockIdx.x * NB;
  int tid = threadIdx.x;
  __shared__ float s_pf[NB*NP];    // 1620
  __shared__ float s_A[NB*192];    // 2304
  __shared__ float s_C0[NQ];       // 1008
  __shared__ float s_C1[336];
  int valid = B_SIZE - b0; if (valid > NB) valid = NB;
  const float* g_pf = ws + OFF_PF + (size_t)b0*NP;
  const float* g_A  = ws + OFF_A  + (size_t)b0*192;
  for (int i = tid; i < valid*NP;  i += 256) s_pf[i] = g_pf[i];
  for (int i = tid; i < valid*192; i += 256) s_A[i]  = g_A[i];
  for (int i = tid; i < NQ;  i += 256) s_C0[i] = ws[OFF_C0 + i];
  for (int i = tid; i < 336; i += 256) s_C1[i] = ws[OFF_C1 + i];
  __syncthreads();
  if (tid >= 252) return;
  int bl = tid/21, j2 = tid - bl*21;
  if (bl >= valid) return;

  float m[48];
  #pragma unroll
  for (int k = 0; k < 48; ++k) m[k] = s_C0[j2*48 + k];

  const float4* Pbase = reinterpret_cast<const float4*>(ws + OFF_P) + j2*12;
  const float* pfr = s_pf + bl*NP;
  for (int p = 0; p < NP; ++p) {
    float s = pfr[p];
    const float4* Pr = Pbase + p*252;
    #pragma unroll
    for (int k4 = 0; k4 < 12; ++k4) {
      float4 pv = Pr[k4];
      m[k4*4+0] += s*pv.x;
      m[k4*4+1] += s*pv.y;
      m[k4*4+2] += s*pv.z;
      m[k4*4+3] += s*pv.w;
    }
  }
  // contraction with A
  int b = b0 + bl;
  float a0 = 0.f, a1 = 0.f, a2 = 0.f;
  const float* Ab = s_A + bl*192;
  #pragma unroll
  for (int j = 0; j < NJOINT; ++j) {
    const float* Aj = Ab + j*12;
    float c1v = s_C1[j2*16 + j];
    float m0 = m[j*3+0], m1 = m[j*3+1], m2 = m[j*3+2];
    a0 += Aj[0]*m0 + Aj[1]*m1 + Aj[2]*m2  + Aj[3]*c1v;
    a1 += Aj[4]*m0 + Aj[5]*m1 + Aj[6]*m2  + Aj[7]*c1v;
    a2 += Aj[8]*m0 + Aj[9]*m1 + Aj[10]*m2 + Aj[11]*c1v;
  }
  out[(b*21 + j2)*3 + 0] = a0 + init_trans[b*3+0];
  out[(b*21 + j2)*3 + 1] = a1 + init_trans[b*3+1];
  out[(b*21 + j2)*3 + 2] = a2 + init_trans[b*3+2];
}

extern "C" void kernel_launch(void* const* d_in, const int* in_sizes, int n_in,
                              void* d_out, int out_size, void* d_ws, size_t ws_size,
                              hipStream_t stream) {
  const float* theta       = (const float*)d_in[0];
  const float* delta_quat  = (const float*)d_in[1];
  const float* user_shape  = (const float*)d_in[2];
  const float* init_quat   = (const float*)d_in[3];
  const float* init_trans  = (const float*)d_in[4];
  const float* v_template  = (const float*)d_in[5];
  const float* shapedirs   = (const float*)d_in[6];
  const float* J_regressor = (const float*)d_in[7];
  const float* posedirs    = (const float*)d_in[8];
  const float* weights     = (const float*)d_in[9];
  float* out = (float*)d_out;
  float* ws  = (float*)d_ws;

  k1_shape<<<1, 256, 0, stream>>>(user_shape, v_template, shapedirs, J_regressor, ws);
  k2_s2<<<336, 256, 0, stream>>>(J_regressor, weights, ws);
  k3_P<<<270, 256, 0, stream>>>(posedirs, ws);
  k4_pose<<<192, 256, 0, stream>>>(theta, delta_quat, init_quat, ws);
  k5_main<<<(B_SIZE + 11)/12, 256, 0, stream>>>(init_trans, ws, out);
}

// Round 2
// 286.319 us; speedup vs baseline: 2.3594x; 2.3594x over previous
//
#include <hip/hip_runtime.h>
#include <math.h>

#define B_SIZE 8192
#define NVERT 778
#define NJOINT 16
#define NJ2 21
#define NP 135
#define NQ 1008  // 21*16*3

// ---- workspace layout (floats) ----
#define OFF_VSHAPED 0        // 2334
#define OFF_JK      2336     // 48
#define OFF_REL     2384     // 48
#define OFF_C1      2432     // 336
#define OFF_C0      2768     // 1008 (16B aligned)
#define OFF_P       3776     // 135*1008 = 136080 (16B aligned)
#define OFF_DT      139856   // 2334*135 = 315090  (dead after k23)
#define OFF_PF      139856   // 8192*135 = 1105920 (overlays DT; k4 runs after k23)
#define OFF_A       1245776  // 8192*192 = 1572864
// total = 2,818,640 floats = 11.27 MB (< previous 12.32 MB working size)

__device__ inline void quat2mat_dev(float qw, float qx, float qy, float qz, float* R) {
  float n = sqrtf(qw*qw + qx*qx + qy*qy + qz*qz);
  float w = qw/n, x = qx/n, y = qy/n, z = qz/n;
  float w2=w*w, x2=x*x, y2=y*y, z2=z*z;
  float wx=w*x, wy=w*y, wz=w*z, xy=x*y, xz=x*z, yz=y*z;
  R[0]=w2+x2-y2-z2; R[1]=2.f*xy-2.f*wz; R[2]=2.f*wy+2.f*xz;
  R[3]=2.f*wz+2.f*xy; R[4]=w2-x2+y2-z2; R[5]=2.f*yz-2.f*wx;
  R[6]=2.f*xz-2.f*wy; R[7]=2.f*wx+2.f*yz; R[8]=w2-x2-y2+z2;
}

__device__ inline void rodrigues_dev(float tx, float ty, float tz, float* R) {
  float ax = tx + 1e-8f, ay = ty + 1e-8f, az = tz + 1e-8f;
  float angle = sqrtf(ax*ax + ay*ay + az*az);
  float nx = tx/angle, ny = ty/angle, nz = tz/angle;
  float half = 0.5f*angle;
  float cw = cosf(half), sw = sinf(half);
  quat2mat_dev(cw, sw*nx, sw*ny, sw*nz, R);
}

__device__ inline void write_A(float* A, const float* G, const float* jk) {
  #pragma unroll
  for (int c = 0; c < 3; ++c) {
    float g0 = G[c*3+0], g1 = G[c*3+1], g2 = G[c*3+2];
    A[c*4+0] = g0; A[c*4+1] = g1; A[c*4+2] = g2;
    A[c*4+3] = G[9+c] - (g0*jk[0] + g1*jk[1] + g2*jk[2]);
  }
}

// K0: transpose posedirs [135][2334] -> DT [2334][135] (LDS-tiled, both sides coalesced)
__global__ void k0_transpose(const float* __restrict__ posedirs, float* __restrict__ ws) {
  __shared__ float tile[32][33];
  int bx = blockIdx.x % 5;   // p tile (5 x 32 >= 135)
  int by = blockIdx.x / 5;   // e tile (73 x 32 >= 2334)
  int p0 = bx*32, e0 = by*32;
  int tx = threadIdx.x & 31, ty = threadIdx.x >> 5;
  #pragma unroll
  for (int r = ty; r < 32; r += 8) {
    int p = p0 + r, e = e0 + tx;
    if (p < NP && e < 2334) tile[r][tx] = posedirs[p*2334 + e];
  }
  __syncthreads();
  float* DT = ws + OFF_DT;
  #pragma unroll
  for (int r = ty; r < 32; r += 8) {
    int e = e0 + r, p = p0 + tx;
    if (p < NP && e < 2334) DT[e*135 + p] = tile[tx][r];
  }
}

// K1: v_shaped, Jk(16x3), rel — one block, parallel reduction over v
__global__ void k1_shape(const float* __restrict__ user_shape,
                         const float* __restrict__ v_template,
                         const float* __restrict__ shapedirs,
                         const float* __restrict__ J_regressor,
                         float* __restrict__ ws) {
  __shared__ float sh[10];
  __shared__ float vs[2334];
  __shared__ float red[256][49];
  __shared__ float jk[48];
  int tid = threadIdx.x;
  if (tid < 10) sh[tid] = user_shape[tid];
  __syncthreads();
  for (int e = tid; e < 2334; e += 256) {
    float acc = v_template[e];
    #pragma unroll
    for (int s = 0; s < 10; ++s) acc += sh[s]*shapedirs[s*2334 + e];
    vs[e] = acc;
    ws[OFF_VSHAPED + e] = acc;
  }
  float part[48];
  #pragma unroll
  for (int k = 0; k < 48; ++k) part[k] = 0.f;
  __syncthreads();
  for (int v = tid; v < NVERT; v += 256) {
    float v0 = vs[3*v+0], v1 = vs[3*v+1], v2 = vs[3*v+2];
    #pragma unroll
    for (int j = 0; j < 16; ++j) {
      float r = J_regressor[v*21 + j];
      part[j*3+0] += r*v0; part[j*3+1] += r*v1; part[j*3+2] += r*v2;
    }
  }
  #pragma unroll
  for (int k = 0; k < 48; ++k) red[tid][k] = part[k];
  __syncthreads();
  if (tid < 48) {
    float s = 0.f;
    for (int t = 0; t < 256; ++t) s += red[t][tid];
    jk[tid] = s;
    ws[OFF_JK + tid] = s;
  }
  __syncthreads();
  if (tid < 48) {
    int j = tid/3, c = tid - j*3;
    float r;
    if (j == 0) r = jk[c];
    else {
      int par = (((j-1) % 3) == 0) ? 0 : (j-1);
      r = jk[j*3+c] - jk[par*3+c];
    }
    ws[OFF_REL + tid] = r;
  }
}

// K23: fused S2 (LDS-only) + C0/C1 + P. Block = 2 q2 rows; grid 168.
__global__ void k23_scp(const float* __restrict__ J_regressor,
                        const float* __restrict__ weights,
                        float* __restrict__ ws) {
  __shared__ float sS2[2][NVERT];
  __shared__ float red[256][9];
  int tid = threadIdx.x;
  int q2a = blockIdx.x*2, q2b = q2a + 1;
  int j2a = q2a >> 4, ja = q2a & 15;
  int j2b = q2b >> 4, jb = q2b & 15;
  const float* vs = ws + OFF_VSHAPED;
  float p8[8];
  #pragma unroll
  for (int k = 0; k < 8; ++k) p8[k] = 0.f;
  for (int v = tid; v < NVERT; v += 256) {
    float v0 = vs[3*v+0], v1 = vs[3*v+1], v2 = vs[3*v+2];
    float sa = J_regressor[v*21 + j2a] * weights[v*16 + ja];
    float sb = J_regressor[v*21 + j2b] * weights[v*16 + jb];
    sS2[0][v] = sa; sS2[1][v] = sb;
    p8[0] += sa; p8[1] += sa*v0; p8[2] += sa*v1; p8[3] += sa*v2;
    p8[4] += sb; p8[5] += sb*v0; p8[6] += sb*v1; p8[7] += sb*v2;
  }
  #pragma unroll
  for (int k = 0; k < 8; ++k) red[tid][k] = p8[k];
  __syncthreads();
  for (int s = 128; s > 0; s >>= 1) {
    if (tid < s) {
      #pragma unroll
      for (int k = 0; k < 8; ++k) red[tid][k] += red[tid+s][k];
    }
    __syncthreads();
  }
  if (tid == 0) {
    ws[OFF_C1 + q2a] = red[0][0];
    ws[OFF_C0 + q2a*3+0] = red[0][1];
    ws[OFF_C0 + q2a*3+1] = red[0][2];
    ws[OFF_C0 + q2a*3+2] = red[0][3];
    ws[OFF_C1 + q2b] = red[0][4];
    ws[OFF_C0 + q2b*3+0] = red[0][5];
    ws[OFF_C0 + q2b*3+1] = red[0][6];
    ws[OFF_C0 + q2b*3+2] = red[0][7];
  }
  // phase B: P[p][q2*3+c] = sum_v S2*DT, lane = p (coalesced DT stream)
  if (tid < NP) {
    int p = tid;
    const float* DT = ws + OFF_DT;
    float a0=0.f,a1=0.f,a2=0.f,b0=0.f,b1=0.f,b2=0.f;
    #pragma unroll 2
    for (int v = 0; v < NVERT; ++v) {
      float d0 = DT[(3*v+0)*135 + p];
      float d1 = DT[(3*v+1)*135 + p];
      float d2 = DT[(3*v+2)*135 + p];
      float sa = sS2[0][v], sb = sS2[1][v];
      a0 += sa*d0; a1 += sa*d1; a2 += sa*d2;
      b0 += sb*d0; b1 += sb*d1; b2 += sb*d2;
    }
    float* P = ws + OFF_P + (size_t)p*NQ;
    P[q2a*3+0] = a0; P[q2a*3+1] = a1; P[q2a*3+2] = a2;
    P[q2b*3+0] = b0; P[q2b*3+1] = b1; P[q2b*3+2] = b2;
  }
}

// K4: per (b, unit): units 0..4 = chains of 3 joints (+pf rows), unit 5 = joint 0.
__global__ void k4_pose(const float* __restrict__ theta,
                        const float* __restrict__ delta_quat,
                        const float* __restrict__ init_quat,
                        float* __restrict__ ws) {
  int gid = blockIdx.x*blockDim.x + threadIdx.x;
  int b = gid/6, u = gid - b*6;
  if (b >= B_SIZE) return;
  const float* Jk  = ws + OFF_JK;
  const float* rel = ws + OFF_REL;
  float* pf   = ws + OFF_PF + (size_t)b*NP;
  float* Aout = ws + OFF_A  + (size_t)b*192;
  float w1=delta_quat[b*4+0], x1=delta_quat[b*4+1], y1=delta_quat[b*4+2], z1=delta_quat[b*4+3];
  float w2=init_quat[0], x2=init_quat[1], y2=init_quat[2], z2=init_quat[3];
  float qw = w1*w2 - x1*x2 - y1*y2 - z1*z2;
  float qx = w1*x2 + x1*w2 + y1*z2 - z1*y2;
  float qy = w1*y2 - x1*z2 + y1*w2 + z1*x2;
  float qz = w1*z2 + x1*y2 - y1*x2 + z1*w2;
  float G[12];
  quat2mat_dev(qw, qx, qy, qz, G);
  G[9]  = rel[0]; G[10] = rel[1]; G[11] = rel[2];
  if (u == 5) {
    write_A(Aout, G, Jk);
    return;
  }
  for (int mstep = 0; mstep < 3; ++mstep) {
    int j = 3*u + 1 + mstep;
    int i = j - 1;
    float tx = theta[b*45 + 3*i + 0];
    float ty = theta[b*45 + 3*i + 1];
    float tz = theta[b*45 + 3*i + 2];
    float R[9];
    rodrigues_dev(tx, ty, tz, R);
    pf[9*i+0] = R[0]-1.f; pf[9*i+1] = R[1];     pf[9*i+2] = R[2];
    pf[9*i+3] = R[3];     pf[9*i+4] = R[4]-1.f; pf[9*i+5] = R[5];
    pf[9*i+6] = R[6];     pf[9*i+7] = R[7];     pf[9*i+8] = R[8]-1.f;
    float nG[12];
    const float* rj = rel + j*3;
    #pragma unroll
    for (int r3 = 0; r3 < 3; ++r3) {
      float a0 = G[r3*3+0], a1 = G[r3*3+1], a2 = G[r3*3+2];
      nG[r3*3+0] = a0*R[0] + a1*R[3] + a2*R[6];
      nG[r3*3+1] = a0*R[1] + a1*R[4] + a2*R[7];
      nG[r3*3+2] = a0*R[2] + a1*R[5] + a2*R[8];
      nG[9+r3]   = G[9+r3] + a0*rj[0] + a1*rj[1] + a2*rj[2];
    }
    #pragma unroll
    for (int k = 0; k < 12; ++k) G[k] = nG[k];
    write_A(Aout + j*12, G, Jk + j*3);
  }
}

// K5: register-tiled GEMM M[16b x 1008q] = C0 + pf @ P, fused with A-contraction.
// Threads: 252 active = 4 b-groups x 63 q-lanes; thread tile = 4b x 4 float4-q.
__global__ __launch_bounds__(256) void k5_main(const float* __restrict__ init_trans,
                                               const float* __restrict__ ws,
                                               float* __restrict__ out) {
  __shared__ __align__(16) float lds[16*1012];  // 64768 B: [pf 16x136 | P 8x1008] then M 16x1012
  int tid = threadIdx.x;
  int b0 = blockIdx.x * 16;
  // stage pf (contiguous 2160 floats, coalesced)
  const float* g_pf = ws + OFF_PF + (size_t)b0*NP;
  for (int i = tid; i < 16*NP; i += 256) {
    int bb = i/NP, p = i - bb*NP;
    lds[bb*136 + p] = g_pf[i];
  }
  int bg = tid/63;
  int tq = tid - bg*63;
  bool act = (tid < 252);
  float4 acc[4][4];
  const float4* C04 = (const float4*)(ws + OFF_C0);
  if (act) {
    #pragma unroll
    for (int k = 0; k < 4; ++k) {
      float4 c0 = C04[tq + 63*k];
      #pragma unroll
      for (int bb = 0; bb < 4; ++bb) acc[bb][k] = c0;
    }
  }
  float4* ldsP4 = (float4*)(lds + 2176);
  const float4* gP4 = (const float4*)(ws + OFF_P);
  for (int pc = 0; pc < NP; pc += 8) {
    int cn = min(8, NP - pc);
    int n4 = cn*252;
    __syncthreads();   // previous chunk fully consumed
    for (int i = tid; i < n4; i += 256) ldsP4[i] = gP4[pc*252 + i];
    __syncthreads();
    if (act) {
      float spf[4][8];
      #pragma unroll
      for (int bb = 0; bb < 4; ++bb)
        for (int pp = 0; pp < cn; ++pp)
          spf[bb][pp] = lds[(bg*4+bb)*136 + pc + pp];
      for (int pp = 0; pp < cn; ++pp) {
        float4 pv[4];
        #pragma unroll
        for (int k = 0; k < 4; ++k) pv[k] = ldsP4[pp*252 + tq + 63*k];
        #pragma unroll
        for (int bb = 0; bb < 4; ++bb) {
          float s = spf[bb][pp];
          #pragma unroll
          for (int k = 0; k < 4; ++k) {
            acc[bb][k].x += s*pv[k].x;
            acc[bb][k].y += s*pv[k].y;
            acc[bb][k].z += s*pv[k].z;
            acc[bb][k].w += s*pv[k].w;
          }
        }
      }
    }
  }
  __syncthreads();
  // spill M to LDS (row stride 1012 floats = 253 float4; conflict-free stores)
  float4* ldsM4 = (float4*)lds;
  if (act) {
    #pragma unroll
    for (int bb = 0; bb < 4; ++bb)
      #pragma unroll
      for (int k = 0; k < 4; ++k)
        ldsM4[(bg*4+bb)*253 + tq + 63*k] = acc[bb][k];
  }
  __syncthreads();
  // contraction: 336 outputs (16 b x 21 j2) in 2 passes
  for (int base = 0; base < 336; base += 256) {
    int idx = base + tid;
    if (idx < 336) {
      int bb = idx/21, j2 = idx - bb*21;
      int b = b0 + bb;
      const float* Ab   = ws + OFF_A + (size_t)b*192;
      const float* mrow = lds + bb*1012 + j2*48;
      const float* c1p  = ws + OFF_C1 + j2*16;
      float a0=0.f, a1=0.f, a2=0.f;
      #pragma unroll
      for (int j = 0; j < 16; ++j) {
        float m0 = mrow[3*j+0], m1 = mrow[3*j+1], m2 = mrow[3*j+2];
        float c1v = c1p[j];
        const float* Aj = Ab + j*12;
        a0 += Aj[0]*m0 + Aj[1]*m1 + Aj[2]*m2  + Aj[3]*c1v;
        a1 += Aj[4]*m0 + Aj[5]*m1 + Aj[6]*m2  + Aj[7]*c1v;
        a2 += Aj[8]*m0 + Aj[9]*m1 + Aj[10]*m2 + Aj[11]*c1v;
      }
      out[(size_t)(b*21 + j2)*3 + 0] = a0 + init_trans[b*3+0];
      out[(size_t)(b*21 + j2)*3 + 1] = a1 + init_trans[b*3+1];
      out[(size_t)(b*21 + j2)*3 + 2] = a2 + init_trans[b*3+2];
    }
  }
}

extern "C" void kernel_launch(void* const* d_in, const int* in_sizes, int n_in,
                              void* d_out, int out_size, void* d_ws, size_t ws_size,
                              hipStream_t stream) {
  const float* theta       = (const float*)d_in[0];
  const float* delta_quat  = (const float*)d_in[1];
  const float* user_shape  = (const float*)d_in[2];
  const float* init_quat   = (const float*)d_in[3];
  const float* init_trans  = (const float*)d_in[4];
  const float* v_template  = (const float*)d_in[5];
  const float* shapedirs   = (const float*)d_in[6];
  const float* J_regressor = (const float*)d_in[7];
  const float* posedirs    = (const float*)d_in[8];
  const float* weights     = (const float*)d_in[9];
  float* out = (float*)d_out;
  float* ws  = (float*)d_ws;

  k0_transpose<<<5*73, 256, 0, stream>>>(posedirs, ws);
  k1_shape<<<1, 256, 0, stream>>>(user_shape, v_template, shapedirs, J_regressor, ws);
  k23_scp<<<168, 256, 0, stream>>>(J_regressor, weights, ws);
  k4_pose<<<192, 256, 0, stream>>>(theta, delta_quat, init_quat, ws);   // after k23 (PF overlays DT)
  k5_main<<<B_SIZE/16, 256, 0, stream>>>(init_trans, ws, out);
}

// Round 3
// 188.741 us; speedup vs baseline: 3.5792x; 1.5170x over previous
//
#include <hip/hip_runtime.h>
#include <math.h>

#define B_SIZE 8192
#define NVERT 778
#define NJOINT 16
#define NJ2 21
#define NP 135
#define NQ 1008   // 21*16*3
#define NEC 416   // 26 groups x 16 ext cols: [0..407] = (c,pp) c=ec/136,pp=ec%136; 408 = C1; 409..415 pad
#define KSPLIT 8

// ---- workspace layout (floats) ----
#define OFF_VSHAPED 0         // 2334
#define OFF_JK      2336      // 48
#define OFF_REL     2384      // 48
#define OFF_C1      2432      // 336
#define OFF_C0      2768      // 1008
#define OFF_P       3776      // 135*1008 = 136080
#define OFF_PPART   139856    // 8*416*336 = 1118208 (dead after k3r)
#define OFF_PF      139856    // 8192*135 = 1105920 (overlays PPART; k4 after k3r)
#define OFF_A       1258064   // 8192*192 = 1572864
// total = 2,830,928 floats = 11.32 MB

__device__ inline void quat2mat_dev(float qw, float qx, float qy, float qz, float* R) {
  float n = sqrtf(qw*qw + qx*qx + qy*qy + qz*qz);
  float w = qw/n, x = qx/n, y = qy/n, z = qz/n;
  float w2=w*w, x2=x*x, y2=y*y, z2=z*z;
  float wx=w*x, wy=w*y, wz=w*z, xy=x*y, xz=x*z, yz=y*z;
  R[0]=w2+x2-y2-z2; R[1]=2.f*xy-2.f*wz; R[2]=2.f*wy+2.f*xz;
  R[3]=2.f*wz+2.f*xy; R[4]=w2-x2+y2-z2; R[5]=2.f*yz-2.f*wx;
  R[6]=2.f*xz-2.f*wy; R[7]=2.f*wx+2.f*yz; R[8]=w2-x2-y2+z2;
}

__device__ inline void rodrigues_dev(float tx, float ty, float tz, float* R) {
  float ax = tx + 1e-8f, ay = ty + 1e-8f, az = tz + 1e-8f;
  float angle = sqrtf(ax*ax + ay*ay + az*az);
  float nx = tx/angle, ny = ty/angle, nz = tz/angle;
  float half = 0.5f*angle;
  float cw = cosf(half), sw = sinf(half);
  quat2mat_dev(cw, sw*nx, sw*ny, sw*nz, R);
}

__device__ inline void write_A(float* A, const float* G, const float* jk) {
  #pragma unroll
  for (int c = 0; c < 3; ++c) {
    float g0 = G[c*3+0], g1 = G[c*3+1], g2 = G[c*3+2];
    A[c*4+0] = g0; A[c*4+1] = g1; A[c*4+2] = g2;
    A[c*4+3] = G[9+c] - (g0*jk[0] + g1*jk[1] + g2*jk[2]);
  }
}

// K1: v_shaped, Jk(16x3), rel — one block
__global__ void k1_shape(const float* __restrict__ user_shape,
                         const float* __restrict__ v_template,
                         const float* __restrict__ shapedirs,
                         const float* __restrict__ J_regressor,
                         float* __restrict__ ws) {
  __shared__ float sh[10];
  __shared__ float vs[2334];
  __shared__ float red[256][49];
  __shared__ float jk[48];
  int tid = threadIdx.x;
  if (tid < 10) sh[tid] = user_shape[tid];
  __syncthreads();
  for (int e = tid; e < 2334; e += 256) {
    float acc = v_template[e];
    #pragma unroll
    for (int s = 0; s < 10; ++s) acc += sh[s]*shapedirs[s*2334 + e];
    vs[e] = acc;
    ws[OFF_VSHAPED + e] = acc;
  }
  float part[48];
  #pragma unroll
  for (int k = 0; k < 48; ++k) part[k] = 0.f;
  __syncthreads();
  for (int v = tid; v < NVERT; v += 256) {
    float v0 = vs[3*v+0], v1 = vs[3*v+1], v2 = vs[3*v+2];
    #pragma unroll
    for (int j = 0; j < 16; ++j) {
      float r = J_regressor[v*21 + j];
      part[j*3+0] += r*v0; part[j*3+1] += r*v1; part[j*3+2] += r*v2;
    }
  }
  #pragma unroll
  for (int k = 0; k < 48; ++k) red[tid][k] = part[k];
  __syncthreads();
  if (tid < 48) {
    float s = 0.f;
    for (int t = 0; t < 256; ++t) s += red[t][tid];
    jk[tid] = s;
    ws[OFF_JK + tid] = s;
  }
  __syncthreads();
  if (tid < 48) {
    int j = tid/3, c = tid - j*3;
    float r;
    if (j == 0) r = jk[c];
    else {
      int par = (((j-1) % 3) == 0) ? 0 : (j-1);
      r = jk[j*3+c] - jk[par*3+c];
    }
    ws[OFF_REL + tid] = r;
  }
}

// K3: split-K GEMM. Ppart[ks][ec][q2] = sum_{v in ks-range} (JR[v][j2]*W[v][j]) * Bext[v][ec]
// grid = 26 col-groups x KSPLIT; block = 192 threads (168 active in MAC: 2 cg x 84 r4; q2 = 4*r4+r)
__global__ __launch_bounds__(192) void k3_pgemm(const float* __restrict__ J_regressor,
                                                const float* __restrict__ weights,
                                                const float* __restrict__ posedirs,
                                                float* __restrict__ ws) {
  __shared__ float sJR[64*21];
  __shared__ float sW [64*16];
  __shared__ float sB [64*16];
  int tid = threadIdx.x;
  int ng = blockIdx.x % 26;
  int ks = blockIdx.x / 26;
  int vbeg = ks*98;
  int vend = min(NVERT, vbeg + 98);
  const float* vs = ws + OFF_VSHAPED;

  int cg = (tid < 84) ? 0 : 1;
  int r4 = (tid < 84) ? tid : tid - 84;
  bool act = (tid < 168);
  int q2 = 4*r4;
  int j2 = q2 >> 4;          // same for the 4 rows
  int jb = q2 & 15;          // j of row 0; rows have j = jb..jb+3

  float acc[4][8];
  #pragma unroll
  for (int r = 0; r < 4; ++r)
    #pragma unroll
    for (int s = 0; s < 8; ++s) acc[r][s] = 0.f;

  for (int v0 = vbeg; v0 < vend; v0 += 64) {
    int kt = min(64, vend - v0);
    __syncthreads();
    for (int idx = tid; idx < kt*21; idx += 192) sJR[idx] = J_regressor[v0*21 + idx];
    for (int idx = tid; idx < kt*16; idx += 192) sW[idx]  = weights[v0*16 + idx];
    for (int idx = tid; idx < 16*64; idx += 192) {
      int s = idx >> 6, iv = idx & 63;
      if (iv < kt) {
        int ec = ng*16 + s;
        float val;
        if (ec >= 408) val = (ec == 408) ? 1.0f : 0.0f;
        else {
          int c = ec / 136, pp = ec - c*136;
          int e = 3*(v0+iv) + c;
          val = (pp == 135) ? vs[e] : posedirs[pp*2334 + e];
        }
        sB[iv*16 + s] = val;
      }
    }
    __syncthreads();
    if (act) {
      for (int i = 0; i < kt; ++i) {
        float jr = sJR[i*21 + j2];
        float4 w4 = *(const float4*)&sW[i*16 + jb];
        float4 b0 = *(const float4*)&sB[i*16 + cg*8];
        float4 b1 = *(const float4*)&sB[i*16 + cg*8 + 4];
        float wv[4] = {w4.x, w4.y, w4.z, w4.w};
        #pragma unroll
        for (int r = 0; r < 4; ++r) {
          float s2 = jr * wv[r];
          acc[r][0] += s2*b0.x; acc[r][1] += s2*b0.y;
          acc[r][2] += s2*b0.z; acc[r][3] += s2*b0.w;
          acc[r][4] += s2*b1.x; acc[r][5] += s2*b1.y;
          acc[r][6] += s2*b1.z; acc[r][7] += s2*b1.w;
        }
      }
    }
  }
  if (act) {
    float* Pp = ws + OFF_PPART + (size_t)ks*NEC*336;
    #pragma unroll
    for (int s = 0; s < 8; ++s) {
      int ec = ng*16 + cg*8 + s;
      float4 v4 = make_float4(acc[0][s], acc[1][s], acc[2][s], acc[3][s]);
      *(float4*)&Pp[ec*336 + q2] = v4;
    }
  }
}

// K3R: reduce KSPLIT partials, scatter to P[pp][q2*3+c], C0, C1
__global__ void k3_reduce(float* __restrict__ ws) {
  int idx = blockIdx.x*256 + threadIdx.x;   // 416*336 = 139776 exact
  int ec = idx / 336, q2 = idx - ec*336;
  const float* Pp = ws + OFF_PPART;
  float s = 0.f;
  #pragma unroll
  for (int ks = 0; ks < KSPLIT; ++ks) s += Pp[(size_t)ks*NEC*336 + ec*336 + q2];
  if (ec < 408) {
    int c = ec / 136, pp = ec - c*136;
    if (pp < 135) ws[OFF_P + (size_t)pp*NQ + q2*3 + c] = s;
    else          ws[OFF_C0 + q2*3 + c] = s;
  } else if (ec == 408) {
    ws[OFF_C1 + q2] = s;
  }
}

// K4: per (b, unit): units 0..4 = chains of 3 joints (+pf rows), unit 5 = joint 0.
__global__ void k4_pose(const float* __restrict__ theta,
                        const float* __restrict__ delta_quat,
                        const float* __restrict__ init_quat,
                        float* __restrict__ ws) {
  int gid = blockIdx.x*blockDim.x + threadIdx.x;
  int b = gid/6, u = gid - b*6;
  if (b >= B_SIZE) return;
  const float* Jk  = ws + OFF_JK;
  const float* rel = ws + OFF_REL;
  float* pf   = ws + OFF_PF + (size_t)b*NP;
  float* Aout = ws + OFF_A  + (size_t)b*192;
  float w1=delta_quat[b*4+0], x1=delta_quat[b*4+1], y1=delta_quat[b*4+2], z1=delta_quat[b*4+3];
  float w2=init_quat[0], x2=init_quat[1], y2=init_quat[2], z2=init_quat[3];
  float qw = w1*w2 - x1*x2 - y1*y2 - z1*z2;
  float qx = w1*x2 + x1*w2 + y1*z2 - z1*y2;
  float qy = w1*y2 - x1*z2 + y1*w2 + z1*x2;
  float qz = w1*z2 + x1*y2 - y1*x2 + z1*w2;
  float G[12];
  quat2mat_dev(qw, qx, qy, qz, G);
  G[9]  = rel[0]; G[10] = rel[1]; G[11] = rel[2];
  if (u == 5) {
    write_A(Aout, G, Jk);
    return;
  }
  for (int mstep = 0; mstep < 3; ++mstep) {
    int j = 3*u + 1 + mstep;
    int i = j - 1;
    float tx = theta[b*45 + 3*i + 0];
    float ty = theta[b*45 + 3*i + 1];
    float tz = theta[b*45 + 3*i + 2];
    float R[9];
    rodrigues_dev(tx, ty, tz, R);
    pf[9*i+0] = R[0]-1.f; pf[9*i+1] = R[1];     pf[9*i+2] = R[2];
    pf[9*i+3] = R[3];     pf[9*i+4] = R[4]-1.f; pf[9*i+5] = R[5];
    pf[9*i+6] = R[6];     pf[9*i+7] = R[7];     pf[9*i+8] = R[8]-1.f;
    float nG[12];
    const float* rj = rel + j*3;
    #pragma unroll
    for (int r3 = 0; r3 < 3; ++r3) {
      float a0 = G[r3*3+0], a1 = G[r3*3+1], a2 = G[r3*3+2];
      nG[r3*3+0] = a0*R[0] + a1*R[3] + a2*R[6];
      nG[r3*3+1] = a0*R[1] + a1*R[4] + a2*R[7];
      nG[r3*3+2] = a0*R[2] + a1*R[5] + a2*R[8];
      nG[9+r3]   = G[9+r3] + a0*rj[0] + a1*rj[1] + a2*rj[2];
    }
    #pragma unroll
    for (int k = 0; k < 12; ++k) G[k] = nG[k];
    write_A(Aout + j*12, G, Jk + j*3);
  }
}

// K5: register-tiled GEMM M[16b x 1008q] = C0 + pf @ P, fused with A-contraction.
__global__ __launch_bounds__(256) void k5_main(const float* __restrict__ init_trans,
                                               const float* __restrict__ ws,
                                               float* __restrict__ out) {
  __shared__ __align__(16) float lds[16*1012];  // [pf 16x136 | P 8x1008] then M 16x1012
  int tid = threadIdx.x;
  int b0 = blockIdx.x * 16;
  const float* g_pf = ws + OFF_PF + (size_t)b0*NP;
  for (int i = tid; i < 16*NP; i += 256) {
    int bb = i/NP, p = i - bb*NP;
    lds[bb*136 + p] = g_pf[i];
  }
  int bg = tid/63;
  int tq = tid - bg*63;
  bool act = (tid < 252);
  float4 acc[4][4];
  const float4* C04 = (const float4*)(ws + OFF_C0);
  if (act) {
    #pragma unroll
    for (int k = 0; k < 4; ++k) {
      float4 c0 = C04[tq + 63*k];
      #pragma unroll
      for (int bb = 0; bb < 4; ++bb) acc[bb][k] = c0;
    }
  }
  float4* ldsP4 = (float4*)(lds + 2176);
  const float4* gP4 = (const float4*)(ws + OFF_P);
  for (int pc = 0; pc < NP; pc += 8) {
    int cn = min(8, NP - pc);
    int n4 = cn*252;
    __syncthreads();
    for (int i = tid; i < n4; i += 256) ldsP4[i] = gP4[pc*252 + i];
    __syncthreads();
    if (act) {
      float spf[4][8];
      #pragma unroll
      for (int bb = 0; bb < 4; ++bb)
        for (int pp = 0; pp < cn; ++pp)
          spf[bb][pp] = lds[(bg*4+bb)*136 + pc + pp];
      for (int pp = 0; pp < cn; ++pp) {
        float4 pv[4];
        #pragma unroll
        for (int k = 0; k < 4; ++k) pv[k] = ldsP4[pp*252 + tq + 63*k];
        #pragma unroll
        for (int bb = 0; bb < 4; ++bb) {
          float s = spf[bb][pp];
          #pragma unroll
          for (int k = 0; k < 4; ++k) {
            acc[bb][k].x += s*pv[k].x;
            acc[bb][k].y += s*pv[k].y;
            acc[bb][k].z += s*pv[k].z;
            acc[bb][k].w += s*pv[k].w;
          }
        }
      }
    }
  }
  __syncthreads();
  float4* ldsM4 = (float4*)lds;
  if (act) {
    #pragma unroll
    for (int bb = 0; bb < 4; ++bb)
      #pragma unroll
      for (int k = 0; k < 4; ++k)
        ldsM4[(bg*4+bb)*253 + tq + 63*k] = acc[bb][k];
  }
  __syncthreads();
  for (int base = 0; base < 336; base += 256) {
    int idx = base + tid;
    if (idx < 336) {
      int bb = idx/21, j2 = idx - bb*21;
      int b = b0 + bb;
      const float* Ab   = ws + OFF_A + (size_t)b*192;
      const float* mrow = lds + bb*1012 + j2*48;
      const float* c1p  = ws + OFF_C1 + j2*16;
      float a0=0.f, a1=0.f, a2=0.f;
      #pragma unroll
      for (int j = 0; j < 16; ++j) {
        float m0 = mrow[3*j+0], m1 = mrow[3*j+1], m2 = mrow[3*j+2];
        float c1v = c1p[j];
        const float* Aj = Ab + j*12;
        a0 += Aj[0]*m0 + Aj[1]*m1 + Aj[2]*m2  + Aj[3]*c1v;
        a1 += Aj[4]*m0 + Aj[5]*m1 + Aj[6]*m2  + Aj[7]*c1v;
        a2 += Aj[8]*m0 + Aj[9]*m1 + Aj[10]*m2 + Aj[11]*c1v;
      }
      out[(size_t)(b*21 + j2)*3 + 0] = a0 + init_trans[b*3+0];
      out[(size_t)(b*21 + j2)*3 + 1] = a1 + init_trans[b*3+1];
      out[(size_t)(b*21 + j2)*3 + 2] = a2 + init_trans[b*3+2];
    }
  }
}

extern "C" void kernel_launch(void* const* d_in, const int* in_sizes, int n_in,
                              void* d_out, int out_size, void* d_ws, size_t ws_size,
                              hipStream_t stream) {
  const float* theta       = (const float*)d_in[0];
  const float* delta_quat  = (const float*)d_in[1];
  const float* user_shape  = (const float*)d_in[2];
  const float* init_quat   = (const float*)d_in[3];
  const float* init_trans  = (const float*)d_in[4];
  const float* v_template  = (const float*)d_in[5];
  const float* shapedirs   = (const float*)d_in[6];
  const float* J_regressor = (const float*)d_in[7];
  const float* posedirs    = (const float*)d_in[8];
  const float* weights     = (const float*)d_in[9];
  float* out = (float*)d_out;
  float* ws  = (float*)d_ws;

  k1_shape<<<1, 256, 0, stream>>>(user_shape, v_template, shapedirs, J_regressor, ws);
  k3_pgemm<<<26*KSPLIT, 192, 0, stream>>>(J_regressor, weights, posedirs, ws);
  k3_reduce<<<546, 256, 0, stream>>>(ws);
  k4_pose<<<192, 256, 0, stream>>>(theta, delta_quat, init_quat, ws);   // after k3_reduce (PF overlays PPART)
  k5_main<<<B_SIZE/16, 256, 0, stream>>>(init_trans, ws, out);
}